// Round 1
// baseline (724.843 us; speedup 1.0000x reference)
//
#include <hip/hip_runtime.h>
#include <hip/hip_bf16.h>

#define NN 100000
#define EE 1600000
#define HIDD 128
#define GG 64

// ---------------- CSR build ----------------

__global__ void k_hist(const int* __restrict__ ei, int* __restrict__ deg) {
    int e = blockIdx.x * blockDim.x + threadIdx.x;
    if (e >= EE) return;
    int d = ei[EE + e];
    atomicAdd(&deg[d], 1);
}

__global__ void k_scan1(const int* __restrict__ deg, int* __restrict__ row_ptr,
                        int* __restrict__ partials) {
    __shared__ int sd[256];
    int t = threadIdx.x;
    int i = blockIdx.x * 256 + t;
    int v = (i < NN) ? deg[i] : 0;
    sd[t] = v;
    __syncthreads();
    for (int off = 1; off < 256; off <<= 1) {
        int x = (t >= off) ? sd[t - off] : 0;
        __syncthreads();
        sd[t] += x;
        __syncthreads();
    }
    if (i < NN) row_ptr[i] = sd[t] - v;           // chunk-local exclusive
    if (t == 255) partials[blockIdx.x] = sd[255]; // chunk total
}

__global__ void k_scan2(int* __restrict__ partials, int nparts) {
    __shared__ int sd[512];
    int t = threadIdx.x;
    int v = (t < nparts) ? partials[t] : 0;
    sd[t] = v;
    __syncthreads();
    for (int off = 1; off < 512; off <<= 1) {
        int x = (t >= off) ? sd[t - off] : 0;
        __syncthreads();
        sd[t] += x;
        __syncthreads();
    }
    partials[t] = sd[t] - v; // exclusive
}

__global__ void k_scan3(int* __restrict__ row_ptr, const int* __restrict__ partials,
                        int* __restrict__ cursor) {
    int i = blockIdx.x * blockDim.x + threadIdx.x;
    if (i < NN) {
        int rp = row_ptr[i] + partials[i >> 8];
        row_ptr[i] = rp;
        cursor[i] = rp;
    }
    if (i == 0) row_ptr[NN] = EE;
}

__global__ void k_scatter(const int* __restrict__ ei, const float* __restrict__ ea,
                          int* __restrict__ cursor, int* __restrict__ csr_src,
                          float* __restrict__ csr_w) {
    int e = blockIdx.x * blockDim.x + threadIdx.x;
    if (e >= EE) return;
    int s = ei[e];
    int d = ei[EE + e];
    int pos = atomicAdd(&cursor[d], 1);
    csr_src[pos] = s;
    csr_w[pos] = ea[e];
}

// ---------------- derived constants ----------------
// cblk layout (floats):
//   0..127   P[k]        (enc_w @ lin_w0)
// 128..255   Q[k]        (enc_b @ lin_w0)
// 256..511   bn_scale[l][k]
// 512..767   bn_shift[l][k]
// 768..771 ps | 772..775 qs | 776..779 pd | 780..783 qd   (layer-0 rank-1 attn)
// 784..791 aeu[l][h] | 792..799 aev[l][h]

__global__ void k_derive(const float* __restrict__ enc_w, const float* __restrict__ enc_b,
                         const float* __restrict__ eenc_w, const float* __restrict__ eenc_b,
                         const float* __restrict__ lin_w, const float* __restrict__ lin_edge_w,
                         const float* __restrict__ att_src, const float* __restrict__ att_dst,
                         const float* __restrict__ att_edge,
                         const float* __restrict__ bn_gamma, const float* __restrict__ bn_beta,
                         const float* __restrict__ bn_mean, const float* __restrict__ bn_var,
                         float* __restrict__ cblk) {
    int t = threadIdx.x; // 128 threads
    __shared__ float red[128];

    float P = 0.f, Q = 0.f;
    for (int j = 0; j < 128; ++j) {
        float w = lin_w[j * 128 + t];
        P += enc_w[j] * w;
        Q += enc_b[j] * w;
    }
    cblk[t] = P;
    cblk[128 + t] = Q;

    for (int l = 0; l < 2; ++l) {
        float sc = bn_gamma[l * 128 + t] * rsqrtf(bn_var[l * 128 + t] + 1e-5f);
        cblk[256 + l * 128 + t] = sc;
        cblk[512 + l * 128 + t] = bn_beta[l * 128 + t] - bn_mean[l * 128 + t] * sc;
    }

    // head reductions helper: v per-channel -> 4 per-head sums at cblk[outbase..outbase+3]
    auto headred = [&](float v, int outbase) {
        red[t] = v;
        __syncthreads();
        if (t < 4) {
            float s = 0.f;
            for (int c = 0; c < 32; ++c) s += red[t * 32 + c];
            cblk[outbase + t] = s;
        }
        __syncthreads();
    };

    headred(P * att_src[t], 768);
    headred(Q * att_src[t], 772);
    headred(P * att_dst[t], 776);
    headred(Q * att_dst[t], 780);

    for (int l = 0; l < 2; ++l) {
        float W1 = 0.f, W2 = 0.f;
        for (int j = 0; j < 128; ++j) {
            float w = lin_edge_w[l * 16384 + j * 128 + t];
            W1 += eenc_w[j] * w;
            W2 += eenc_b[j] * w;
        }
        headred(W1 * att_edge[l * 128 + t], 784 + l * 4);
        headred(W2 * att_edge[l * 128 + t], 792 + l * 4);
    }
}

// ---------------- layer 0 (rank-1 everywhere) ----------------

__global__ void k_l0_edge(const float* __restrict__ x, const int* __restrict__ row_ptr,
                          const int* __restrict__ csr_src, const float* __restrict__ csr_w,
                          const float* __restrict__ cblk, float* __restrict__ tmp0) {
    int n = blockIdx.x * blockDim.x + threadIdx.x;
    if (n >= NN) return;
    float xn = x[n];
    float ps[4], qs[4], ad[4], au[4];
    #pragma unroll
    for (int h = 0; h < 4; ++h) {
        ps[h] = cblk[768 + h];
        qs[h] = cblk[772 + h];
        // fold a_d (rank-1) + aev0 into one per-head constant
        ad[h] = xn * cblk[776 + h] + cblk[780 + h] + cblk[792 + h];
        au[h] = cblk[784 + h];
    }
    float s[4] = {0.f, 0.f, 0.f, 0.f}, sx[4] = {0.f, 0.f, 0.f, 0.f};
    int jb = row_ptr[n], je = row_ptr[n + 1];
    for (int j = jb; j < je; ++j) {
        int sj = csr_src[j];
        float wj = csr_w[j];
        float xsv = x[sj];
        #pragma unroll
        for (int h = 0; h < 4; ++h) {
            float a = xsv * ps[h] + qs[h] + ad[h] + wj * au[h];
            a = (a > 0.f) ? a : 0.2f * a;
            float p = __expf(a);
            s[h] += p;
            sx[h] += p * xsv;
        }
    }
    #pragma unroll
    for (int h = 0; h < 4; ++h) {
        tmp0[n * 8 + h] = s[h];
        tmp0[n * 8 + 4 + h] = sx[h];
    }
}

__global__ void k_l0_epi(const float* __restrict__ x, const float* __restrict__ enc_w,
                         const float* __restrict__ enc_b, const float* __restrict__ conv_b,
                         const float* __restrict__ cblk, const float* __restrict__ tmp0,
                         float* __restrict__ hbuf) {
    int idx = blockIdx.x * blockDim.x + threadIdx.x;
    if (idx >= NN * HIDD) return;
    int n = idx >> 7, k = idx & 127, h = (k >> 5) & 3;
    float s = tmp0[n * 8 + h];
    float sx = tmp0[n * 8 + 4 + h];
    float inv = 1.f / (s + 1e-16f);
    float agg = (sx * cblk[k] + s * cblk[128 + k]) * inv + conv_b[k];
    float o = agg * cblk[256 + k] + cblk[512 + k];
    float hv = fmaxf(o, 0.f) + x[n] * enc_w[k] + enc_b[k];
    hbuf[idx] = hv;
}

// ---------------- layer 1 GEMM: xs = h @ lin_w[1]  (fp32, LDS-tiled) ----------------

__global__ __launch_bounds__(256) void k_gemm(const float* __restrict__ A,
                                              const float* __restrict__ Wg,
                                              float* __restrict__ xs) {
    __shared__ float sW[128 * 128]; // 64 KiB
    __shared__ float sA[32 * 128];  // 16 KiB
    int t = threadIdx.x;
    const float4* W4 = (const float4*)Wg;
    float4* sW4 = (float4*)sW;
    for (int i = t; i < 4096; i += 256) sW4[i] = W4[i];
    const float4* A4 = (const float4*)(A + (size_t)blockIdx.x * 32 * 128);
    float4* sA4 = (float4*)sA;
    for (int i = t; i < 1024; i += 256) sA4[i] = A4[i];
    __syncthreads();

    int cg = t & 15, rp = t >> 4;
    int c0 = cg * 8, r0 = rp * 2;
    float acc0[8] = {0.f, 0.f, 0.f, 0.f, 0.f, 0.f, 0.f, 0.f};
    float acc1[8] = {0.f, 0.f, 0.f, 0.f, 0.f, 0.f, 0.f, 0.f};
    #pragma unroll 4
    for (int k = 0; k < 128; ++k) {
        float a0 = sA[r0 * 128 + k];
        float a1 = sA[r0 * 128 + 128 + k];
        const float4 w0 = *(const float4*)&sW[k * 128 + c0];
        const float4 w1 = *(const float4*)&sW[k * 128 + c0 + 4];
        acc0[0] += a0 * w0.x; acc0[1] += a0 * w0.y; acc0[2] += a0 * w0.z; acc0[3] += a0 * w0.w;
        acc0[4] += a0 * w1.x; acc0[5] += a0 * w1.y; acc0[6] += a0 * w1.z; acc0[7] += a0 * w1.w;
        acc1[0] += a1 * w0.x; acc1[1] += a1 * w0.y; acc1[2] += a1 * w0.z; acc1[3] += a1 * w0.w;
        acc1[4] += a1 * w1.x; acc1[5] += a1 * w1.y; acc1[6] += a1 * w1.z; acc1[7] += a1 * w1.w;
    }
    float* out = xs + ((size_t)blockIdx.x * 32 + r0) * 128 + c0;
    float4 o;
    o.x = acc0[0]; o.y = acc0[1]; o.z = acc0[2]; o.w = acc0[3]; *(float4*)out = o;
    o.x = acc0[4]; o.y = acc0[5]; o.z = acc0[6]; o.w = acc0[7]; *(float4*)(out + 4) = o;
    o.x = acc1[0]; o.y = acc1[1]; o.z = acc1[2]; o.w = acc1[3]; *(float4*)(out + 128) = o;
    o.x = acc1[4]; o.y = acc1[5]; o.z = acc1[6]; o.w = acc1[7]; *(float4*)(out + 132) = o;
}

// a_s1[n,h], a_d1[n,h] from xs row (block per node, 128 threads)
__global__ void k_asad(const float* __restrict__ xs, const float* __restrict__ att_src1,
                       const float* __restrict__ att_dst1, float* __restrict__ a_s,
                       float* __restrict__ a_d) {
    int n = blockIdx.x;
    int t = threadIdx.x;
    float v = xs[(size_t)n * 128 + t];
    float vs = v * att_src1[t];
    float vd = v * att_dst1[t];
    #pragma unroll
    for (int off = 16; off; off >>= 1) {
        vs += __shfl_down(vs, off);
        vd += __shfl_down(vd, off);
    }
    if ((t & 31) == 0) {
        a_s[n * 4 + (t >> 5)] = vs;
        a_d[n * 4 + (t >> 5)] = vd;
    }
}

// ---------------- layer 1 aggregation: wave per node ----------------

__global__ __launch_bounds__(256) void k_l1_agg(const float* __restrict__ xs,
                                                const float* __restrict__ a_s,
                                                const float* __restrict__ a_d,
                                                const int* __restrict__ row_ptr,
                                                const int* __restrict__ csr_src,
                                                const float* __restrict__ csr_w,
                                                const float* __restrict__ cblk,
                                                const float* __restrict__ conv_b,
                                                float* __restrict__ hbuf) {
    int wid = threadIdx.x >> 6;
    int lane = threadIdx.x & 63;
    int n = blockIdx.x * 4 + wid;
    if (n >= NN) return;
    int k0 = lane, k1 = lane + 64;
    int h0 = lane >> 5, h1 = h0 + 2;

    float ad0 = a_d[n * 4 + h0] + cblk[796 + h0]; // + aev1
    float ad1 = a_d[n * 4 + h1] + cblk[796 + h1];
    float au0 = cblk[788 + h0]; // aeu1
    float au1 = cblk[788 + h1];

    float acc0 = 0.f, acc1 = 0.f, s0 = 0.f, s1 = 0.f;
    int jb = row_ptr[n], je = row_ptr[n + 1];
    for (int j = jb; j < je; ++j) {
        int sj = csr_src[j];
        float wj = csr_w[j];
        float al0 = a_s[sj * 4 + h0] + ad0 + wj * au0;
        float al1 = a_s[sj * 4 + h1] + ad1 + wj * au1;
        al0 = (al0 > 0.f) ? al0 : 0.2f * al0;
        al1 = (al1 > 0.f) ? al1 : 0.2f * al1;
        float p0 = __expf(al0);
        float p1 = __expf(al1);
        s0 += p0;
        s1 += p1;
        const float* xr = xs + (size_t)sj * 128;
        acc0 += p0 * xr[k0];
        acc1 += p1 * xr[k1];
    }
    float o0 = acc0 / (s0 + 1e-16f) + conv_b[128 + k0];
    float o1 = acc1 / (s1 + 1e-16f) + conv_b[128 + k1];
    o0 = o0 * cblk[256 + 128 + k0] + cblk[512 + 128 + k0];
    o1 = o1 * cblk[256 + 128 + k1] + cblk[512 + 128 + k1];
    size_t base = (size_t)n * 128;
    float hv0 = fmaxf(o0, 0.f) + hbuf[base + k0];
    float hv1 = fmaxf(o1, 0.f) + hbuf[base + k1];
    hbuf[base + k0] = hv0;
    hbuf[base + k1] = hv1;
}

// ---------------- pooling + head ----------------

__global__ void k_pool(const float* __restrict__ hbuf, const int* __restrict__ batch,
                       float* __restrict__ pooled, float* __restrict__ gcnt) {
    int t = threadIdx.x; // 128
    int n0 = blockIdx.x * 256;
    int nend = min(n0 + 256, NN);
    float acc = 0.f;
    int run = 0;
    int gprev = batch[n0];
    for (int n = n0; n < nend; ++n) {
        int g = batch[n];
        if (g != gprev) {
            atomicAdd(&pooled[gprev * 128 + t], acc);
            if (t == 0) atomicAdd(&gcnt[gprev], (float)run);
            acc = 0.f;
            run = 0;
            gprev = g;
        }
        acc += hbuf[(size_t)n * 128 + t];
        run++;
    }
    atomicAdd(&pooled[gprev * 128 + t], acc);
    if (t == 0) atomicAdd(&gcnt[gprev], (float)run);
}

__global__ void k_head(const float* __restrict__ pooled, const float* __restrict__ gcnt,
                       const float* __restrict__ w1, const float* __restrict__ b1,
                       const float* __restrict__ w2, const float* __restrict__ b2,
                       float* __restrict__ out) {
    int g = blockIdx.x;
    int j = threadIdx.x; // 64
    float inv = 1.f / fmaxf(gcnt[g], 1.f);
    float acc = b1[j];
    for (int k = 0; k < 128; ++k) acc += pooled[g * 128 + k] * inv * w1[k * 64 + j];
    float z = fmaxf(acc, 0.f);
    float v = z * w2[j];
    #pragma unroll
    for (int off = 32; off; off >>= 1) v += __shfl_down(v, off);
    if (j == 0) out[g] = 1.f / (1.f + __expf(-(v + b2[0])));
}

// ---------------- launcher ----------------

extern "C" void kernel_launch(void* const* d_in, const int* in_sizes, int n_in,
                              void* d_out, int out_size, void* d_ws, size_t ws_size,
                              hipStream_t stream) {
    const float* x        = (const float*)d_in[0];
    const float* ea       = (const float*)d_in[1];
    const int*   ei       = (const int*)d_in[2];
    const int*   batch    = (const int*)d_in[3];
    const float* enc_w    = (const float*)d_in[4];
    const float* enc_b    = (const float*)d_in[5];
    const float* eenc_w   = (const float*)d_in[6];
    const float* eenc_b   = (const float*)d_in[7];
    const float* lin_w    = (const float*)d_in[8];
    const float* att_src  = (const float*)d_in[9];
    const float* att_dst  = (const float*)d_in[10];
    const float* att_edge = (const float*)d_in[11];
    const float* lin_edge = (const float*)d_in[12];
    const float* conv_b   = (const float*)d_in[13];
    const float* bn_gamma = (const float*)d_in[14];
    const float* bn_beta  = (const float*)d_in[15];
    const float* bn_mean  = (const float*)d_in[16];
    const float* bn_var   = (const float*)d_in[17];
    const float* w1       = (const float*)d_in[18];
    const float* b1       = (const float*)d_in[19];
    const float* w2       = (const float*)d_in[20];
    const float* b2       = (const float*)d_in[21];
    float* out = (float*)d_out;

    char* ws = (char*)d_ws;
    size_t off = 0;
    auto alloc = [&](size_t bytes) {
        size_t o = off;
        off = (off + bytes + 511) & ~(size_t)511;
        return o;
    };
    int*   deg      = (int*)(ws + alloc((size_t)NN * 4));
    int*   row_ptr  = (int*)(ws + alloc((size_t)(NN + 1) * 4));
    int*   cursor   = (int*)(ws + alloc((size_t)NN * 4));
    int*   partials = (int*)(ws + alloc(512 * 4));
    int*   csr_src  = (int*)(ws + alloc((size_t)EE * 4));
    float* csr_w    = (float*)(ws + alloc((size_t)EE * 4));
    float* cblk     = (float*)(ws + alloc(1024 * 4));
    float* tmp0     = (float*)(ws + alloc((size_t)NN * 8 * 4));
    float* a_s      = (float*)(ws + alloc((size_t)NN * 4 * 4));
    float* a_d      = (float*)(ws + alloc((size_t)NN * 4 * 4));
    float* hbuf     = (float*)(ws + alloc((size_t)NN * HIDD * 4));
    float* xsb      = (float*)(ws + alloc((size_t)NN * HIDD * 4));
    float* pooled   = (float*)(ws + alloc(GG * HIDD * 4 + GG * 4)); // pooled + gcnt adjacent
    float* gcnt     = pooled + GG * HIDD;

    hipMemsetAsync(deg, 0, (size_t)NN * 4, stream);
    hipMemsetAsync(pooled, 0, GG * HIDD * 4 + GG * 4, stream);

    const int nparts = (NN + 255) / 256; // 391

    k_hist<<<(EE + 255) / 256, 256, 0, stream>>>(ei, deg);
    k_scan1<<<nparts, 256, 0, stream>>>(deg, row_ptr, partials);
    k_scan2<<<1, 512, 0, stream>>>(partials, nparts);
    k_scan3<<<nparts, 256, 0, stream>>>(row_ptr, partials, cursor);
    k_scatter<<<(EE + 255) / 256, 256, 0, stream>>>(ei, ea, cursor, csr_src, csr_w);

    k_derive<<<1, 128, 0, stream>>>(enc_w, enc_b, eenc_w, eenc_b, lin_w, lin_edge,
                                    att_src, att_dst, att_edge,
                                    bn_gamma, bn_beta, bn_mean, bn_var, cblk);

    k_l0_edge<<<nparts, 256, 0, stream>>>(x, row_ptr, csr_src, csr_w, cblk, tmp0);
    k_l0_epi<<<(NN * HIDD + 255) / 256, 256, 0, stream>>>(x, enc_w, enc_b, conv_b, cblk,
                                                          tmp0, hbuf);

    k_gemm<<<NN / 32, 256, 0, stream>>>(hbuf, lin_w + 16384, xsb);
    k_asad<<<NN, 128, 0, stream>>>(xsb, att_src + 128, att_dst + 128, a_s, a_d);
    k_l1_agg<<<(NN + 3) / 4, 256, 0, stream>>>(xsb, a_s, a_d, row_ptr, csr_src, csr_w,
                                               cblk, conv_b, hbuf);

    k_pool<<<nparts, 128, 0, stream>>>(hbuf, batch, pooled, gcnt);
    k_head<<<GG, 64, 0, stream>>>(pooled, gcnt, w1, b1, w2, b2, out);
}